// Round 4
// baseline (631.417 us; speedup 1.0000x reference)
//
#include <hip/hip_runtime.h>
#include <hip/hip_bf16.h>

typedef unsigned short u16;
typedef unsigned int   u32;
typedef __attribute__((ext_vector_type(8))) short short8;   // 8 x bf16 bits (4 VGPR)
typedef __attribute__((ext_vector_type(4))) float f32x4;    // MFMA 16x16 accumulator

__device__ __forceinline__ float bf2f(u16 u) {
  union { u32 i; float f; } v; v.i = ((u32)u) << 16; return v.f;
}
// round-to-nearest-even f32 -> bf16 (finite inputs only)
__device__ __forceinline__ u16 f2bf(float f) {
  u32 u = __float_as_uint(f);
  u32 r = (u + 0x7fffu + ((u >> 16) & 1u)) >> 16;
  return (u16)r;
}
// load 8 consecutive fp32, convert to bf16 bits (two float4 vector loads)
__device__ __forceinline__ short8 loadcvt8(const float* __restrict__ p) {
  const float4 a = *(const float4*)(p);
  const float4 b = *(const float4*)(p + 4);
  short8 r;
  r[0] = (short)f2bf(a.x); r[1] = (short)f2bf(a.y);
  r[2] = (short)f2bf(a.z); r[3] = (short)f2bf(a.w);
  r[4] = (short)f2bf(b.x); r[5] = (short)f2bf(b.y);
  r[6] = (short)f2bf(b.z); r[7] = (short)f2bf(b.w);
  return r;
}

// ---------------------------------------------------------------------------
// CPB MLP: table[225][8] = relu(coords @ w1^T + b1) @ w2^T   (fp32 math)
// ---------------------------------------------------------------------------
__global__ __launch_bounds__(256) void cpb_kernel(
    const float* __restrict__ ct, const float* __restrict__ w1,
    const float* __restrict__ b1, const float* __restrict__ w2,
    float* __restrict__ table) {
  const int r = blockIdx.x;            // 0..224
  const int t = threadIdx.x;           // 0..255
  const int lane = t & 63, wave = t >> 6;
  const float c0 = ct[r * 2 + 0];
  const float c1 = ct[r * 2 + 1];
  float acc[8] = {0.f, 0.f, 0.f, 0.f, 0.f, 0.f, 0.f, 0.f};
  for (int j = t; j < 512; j += 256) {
    float hid = fmaxf(c0 * w1[j * 2] + c1 * w1[j * 2 + 1] + b1[j], 0.f);
#pragma unroll
    for (int hh = 0; hh < 8; ++hh) acc[hh] += hid * w2[hh * 512 + j];
  }
#pragma unroll
  for (int hh = 0; hh < 8; ++hh)
#pragma unroll
    for (int off = 1; off < 64; off <<= 1) acc[hh] += __shfl_xor(acc[hh], off);
  __shared__ float red[4][8];
  if (lane == 0)
#pragma unroll
    for (int hh = 0; hh < 8; ++hh) red[wave][hh] = acc[hh];
  __syncthreads();
  if (t < 8) table[r * 8 + t] = red[0][t] + red[1][t] + red[2][t] + red[3][t];
}

// bias16[h][i*64+j] = 16*sigmoid(table[rel_idx[i*64+j]][h])
__global__ __launch_bounds__(256) void gather_kernel(
    const float* __restrict__ table, const int* __restrict__ rel,
    float* __restrict__ bias16) {
  const int e = blockIdx.x * 256 + threadIdx.x;  // 8*4096 = 32768
  const int hh = e >> 12, ij = e & 4095;
  const float v = table[rel[ij] * 8 + hh];
  bias16[e] = 16.f * (1.f / (1.f + __expf(-v)));
}

// ---------------------------------------------------------------------------
// QKV GEMM (one 256-window chunk): C[m][n] = sum_k x[row0+m][k]*w[n][k] + bias,
// scattered to Q/K/V [256][H][64][32] bf16.  fp32 inputs -> bf16 LDS tiles.
// ---------------------------------------------------------------------------
#define BK 32
__global__ __launch_bounds__(256) void gemm_qkv(
    const float* __restrict__ X,   // full [131072][256] fp32
    const float* __restrict__ Wq,  // [768][256] fp32
    const float* __restrict__ qb, const float* __restrict__ vb,
    int row0,
    u16* __restrict__ Q, u16* __restrict__ K, u16* __restrict__ V) {
  __shared__ __attribute__((aligned(16))) u16 lA[128 * BK];
  __shared__ __attribute__((aligned(16))) u16 lB[128 * BK];
  const int tid = threadIdx.x;
  const int wave = tid >> 6, lane = tid & 63;
  const int l15 = lane & 15, l4 = lane >> 4;
  const int m0 = blockIdx.x * 128;
  const int n0 = blockIdx.y * 128;
  const int wm = (wave & 1) * 64;
  const int wn = (wave >> 1) * 64;
  const int sr = tid >> 1;          // staging row 0..127
  const int sc = (tid & 1) * 16;    // staging col 0 or 16

  f32x4 acc[4][4];
#pragma unroll
  for (int i = 0; i < 4; ++i)
#pragma unroll
    for (int j = 0; j < 4; ++j) acc[i][j] = (f32x4){0.f, 0.f, 0.f, 0.f};

  for (int k0 = 0; k0 < 256; k0 += BK) {
    __syncthreads();  // previous iter done reading LDS
    short8 a0 = loadcvt8(X  + (size_t)(row0 + m0 + sr) * 256 + k0 + sc);
    short8 a1 = loadcvt8(X  + (size_t)(row0 + m0 + sr) * 256 + k0 + sc + 8);
    short8 b0 = loadcvt8(Wq + (size_t)(n0 + sr) * 256 + k0 + sc);
    short8 b1 = loadcvt8(Wq + (size_t)(n0 + sr) * 256 + k0 + sc + 8);
    *(short8*)&lA[sr * BK + sc]     = a0;
    *(short8*)&lA[sr * BK + sc + 8] = a1;
    *(short8*)&lB[sr * BK + sc]     = b0;
    *(short8*)&lB[sr * BK + sc + 8] = b1;
    __syncthreads();

    short8 af[4], bf[4];
#pragma unroll
    for (int i = 0; i < 4; ++i)
      af[i] = *(const short8*)&lA[(wm + i * 16 + l15) * BK + l4 * 8];
#pragma unroll
    for (int j = 0; j < 4; ++j)
      bf[j] = *(const short8*)&lB[(wn + j * 16 + l15) * BK + l4 * 8];
#pragma unroll
    for (int i = 0; i < 4; ++i)
#pragma unroll
      for (int j = 0; j < 4; ++j)
        acc[i][j] = __builtin_amdgcn_mfma_f32_16x16x32_bf16(af[i], bf[j], acc[i][j], 0, 0, 0);
  }

  // epilogue: n -> (which, head, d); m -> (window b, token t)
#pragma unroll
  for (int i = 0; i < 4; ++i) {
    const int mrow = m0 + wm + i * 16 + l4 * 4;
#pragma unroll
    for (int j = 0; j < 4; ++j) {
      const int n = n0 + wn + j * 16 + l15;
      const int which = n >> 8;
      const int c = n & 255;
      const float bias = (which == 0) ? qb[c] : (which == 2) ? vb[c] : 0.f;
      u16* dst = (which == 0) ? Q : (which == 1) ? K : V;
      const int h = c >> 5, d = c & 31;
#pragma unroll
      for (int r = 0; r < 4; ++r) {
        const int m = mrow + r;
        const int b = m >> 6, t = m & 63;
        dst[(((size_t)b * 8 + h) * 64 + t) * 32 + d] = f2bf(acc[i][j][r] + bias);
      }
    }
  }
}

// ---------------------------------------------------------------------------
// Fused attention + proj: one block per window.  Per head: normalize q,k ->
// S=Qn.Kn^T (MFMA) -> *scale +bias +mask -> softmax -> P.V (MFMA) -> o_lds;
// then proj GEMM from o_lds, fp32 output.
// ---------------------------------------------------------------------------
__global__ __launch_bounds__(256) void attn_proj(
    const u16* __restrict__ Q, const u16* __restrict__ K, const u16* __restrict__ V,
    const float* __restrict__ mask,  // [64][64][64] fp32
    const float* __restrict__ bias16,// [8][4096] fp32
    const float* __restrict__ lsc,   // [8] fp32
    const float* __restrict__ Wp,    // [256][256] fp32
    const float* __restrict__ pb,    // [256] fp32
    float* __restrict__ out) {       // [16384][256] fp32 (chunk base)
  constexpr int OS = 264;  // o_lds row stride
  __shared__ __attribute__((aligned(16))) u16 q_lds[64 * 32];
  __shared__ __attribute__((aligned(16))) u16 k_lds[64 * 32];
  __shared__ __attribute__((aligned(16))) u16 vt_lds[32 * 72];
  __shared__ __attribute__((aligned(16))) u16 p_lds[64 * 72];
  __shared__ __attribute__((aligned(16))) u16 o_lds[64 * OS];

  const int b = blockIdx.x;        // chunk-local window id (256 ≡ 0 mod 64)
  const int w = b & 63;            // mask window index
  const int tid = threadIdx.x;
  const int wave = tid >> 6, lane = tid & 63;
  const int l15 = lane & 15, l4 = lane >> 4;
  const int lrow = tid >> 2;        // 0..63
  const int lcol = (tid & 3) * 8;   // 0,8,16,24

  for (int h = 0; h < 8; ++h) {
    const size_t base = ((size_t)b * 8 + h) * 2048;
    __syncthreads();  // prev head done reading q/k/vt/p

    {  // stage q (normalized), k (normalized), v^T
      short8 qv = *(const short8*)(Q + base + lrow * 32 + lcol);
      float f[8]; float ss = 0.f;
#pragma unroll
      for (int j = 0; j < 8; ++j) { f[j] = bf2f((u16)qv[j]); ss += f[j] * f[j]; }
      ss += __shfl_xor(ss, 1); ss += __shfl_xor(ss, 2);
      float inv = 1.f / fmaxf(sqrtf(ss), 1e-12f);
      short8 st;
#pragma unroll
      for (int j = 0; j < 8; ++j) st[j] = (short)f2bf(f[j] * inv);
      *(short8*)&q_lds[lrow * 32 + lcol] = st;

      short8 kv = *(const short8*)(K + base + lrow * 32 + lcol);
      ss = 0.f;
#pragma unroll
      for (int j = 0; j < 8; ++j) { f[j] = bf2f((u16)kv[j]); ss += f[j] * f[j]; }
      ss += __shfl_xor(ss, 1); ss += __shfl_xor(ss, 2);
      inv = 1.f / fmaxf(sqrtf(ss), 1e-12f);
#pragma unroll
      for (int j = 0; j < 8; ++j) st[j] = (short)f2bf(f[j] * inv);
      *(short8*)&k_lds[lrow * 32 + lcol] = st;

      short8 vv = *(const short8*)(V + base + lrow * 32 + lcol);
#pragma unroll
      for (int j = 0; j < 8; ++j) vt_lds[(lcol + j) * 72 + lrow] = (u16)vv[j];
    }
    __syncthreads();

    // S tiles: wave owns rows [wave*16, wave*16+16) x all 64 cols
    const float scale = expf(fminf(lsc[h], 4.60517018598809136804f));
    short8 aq = *(const short8*)&q_lds[(wave * 16 + l15) * 32 + l4 * 8];
    f32x4 s[4];
#pragma unroll
    for (int nb = 0; nb < 4; ++nb) {
      short8 bk = *(const short8*)&k_lds[(nb * 16 + l15) * 32 + l4 * 8];
      f32x4 z = {0.f, 0.f, 0.f, 0.f};
      s[nb] = __builtin_amdgcn_mfma_f32_16x16x32_bf16(aq, bk, z, 0, 0, 0);
    }

    const float* brow = bias16 + h * 4096;
    const float* mrow = mask + (size_t)w * 4096;
    float pm[4][4];  // [nb][r]
#pragma unroll
    for (int r = 0; r < 4; ++r) {
      const int i = wave * 16 + l4 * 4 + r;
      float v0[4]; float mx = -3.0e38f;
#pragma unroll
      for (int nb = 0; nb < 4; ++nb) {
        const int j = nb * 16 + l15;
        float sv = s[nb][r] * scale + brow[i * 64 + j] + mrow[i * 64 + j];
        v0[nb] = sv; mx = fmaxf(mx, sv);
      }
      mx = fmaxf(mx, __shfl_xor(mx, 1)); mx = fmaxf(mx, __shfl_xor(mx, 2));
      mx = fmaxf(mx, __shfl_xor(mx, 4)); mx = fmaxf(mx, __shfl_xor(mx, 8));
      float sum = 0.f;
#pragma unroll
      for (int nb = 0; nb < 4; ++nb) { v0[nb] = __expf(v0[nb] - mx); sum += v0[nb]; }
      sum += __shfl_xor(sum, 1); sum += __shfl_xor(sum, 2);
      sum += __shfl_xor(sum, 4); sum += __shfl_xor(sum, 8);
      const float isum = 1.f / sum;
#pragma unroll
      for (int nb = 0; nb < 4; ++nb) pm[nb][r] = v0[nb] * isum;
    }
#pragma unroll
    for (int nb = 0; nb < 4; ++nb)
#pragma unroll
      for (int r = 0; r < 4; ++r)
        p_lds[(wave * 16 + l4 * 4 + r) * 72 + nb * 16 + l15] = f2bf(pm[nb][r]);
    __syncthreads();

    // O = P @ V : rows wave*16.., cols d 0..31 (2 n-tiles), K=64 (2 k-steps)
    f32x4 oa[2] = {{0.f, 0.f, 0.f, 0.f}, {0.f, 0.f, 0.f, 0.f}};
#pragma unroll
    for (int kb = 0; kb < 2; ++kb) {
      short8 pa = *(const short8*)&p_lds[(wave * 16 + l15) * 72 + kb * 32 + l4 * 8];
#pragma unroll
      for (int nb = 0; nb < 2; ++nb) {
        short8 vb8 = *(const short8*)&vt_lds[(nb * 16 + l15) * 72 + kb * 32 + l4 * 8];
        oa[nb] = __builtin_amdgcn_mfma_f32_16x16x32_bf16(pa, vb8, oa[nb], 0, 0, 0);
      }
    }
#pragma unroll
    for (int nb = 0; nb < 2; ++nb)
#pragma unroll
      for (int r = 0; r < 4; ++r) {
        const int m = wave * 16 + l4 * 4 + r;
        const int d = nb * 16 + l15;
        o_lds[m * OS + h * 32 + d] = f2bf(oa[nb][r]);
      }
  }
  __syncthreads();  // o_lds complete across all waves

  // proj: wave owns n-range [wave*64, wave*64+64), all 64 rows; K=256
  const int n0 = wave * 64;
  f32x4 pacc[4][4];
#pragma unroll
  for (int i = 0; i < 4; ++i)
#pragma unroll
    for (int j = 0; j < 4; ++j) pacc[i][j] = (f32x4){0.f, 0.f, 0.f, 0.f};
  for (int k0 = 0; k0 < 256; k0 += 32) {
    short8 afr[4];
#pragma unroll
    for (int mi = 0; mi < 4; ++mi)
      afr[mi] = *(const short8*)&o_lds[(mi * 16 + l15) * OS + k0 + l4 * 8];
#pragma unroll
    for (int nj = 0; nj < 4; ++nj) {
      short8 bfr = loadcvt8(Wp + (size_t)(n0 + nj * 16 + l15) * 256 + k0 + l4 * 8);
#pragma unroll
      for (int mi = 0; mi < 4; ++mi)
        pacc[mi][nj] = __builtin_amdgcn_mfma_f32_16x16x32_bf16(afr[mi], bfr, pacc[mi][nj], 0, 0, 0);
    }
  }
#pragma unroll
  for (int mi = 0; mi < 4; ++mi)
#pragma unroll
    for (int nj = 0; nj < 4; ++nj) {
      const int n = n0 + nj * 16 + l15;
      const float bias = pb[n];
#pragma unroll
      for (int r = 0; r < 4; ++r) {
        const int m = mi * 16 + l4 * 4 + r;
        out[((size_t)b * 64 + m) * 256 + n] = pacc[mi][nj][r] + bias;
      }
    }
}

// ---------------------------------------------------------------------------
// ws layout (8 chunks of 256 windows; ws footprint <= ~26.2 MB):
//   [0,7.2K)    table fp32 | [16K,147K) bias16 fp32 | [1M..] Qc/Kc/Vc 8.39 MB ea
// ---------------------------------------------------------------------------
extern "C" void kernel_launch(void* const* d_in, const int* in_sizes, int n_in,
                              void* d_out, int out_size, void* d_ws, size_t ws_size,
                              hipStream_t stream) {
  (void)in_sizes; (void)n_in; (void)out_size; (void)ws_size;
  const float* x    = (const float*)d_in[0];
  const float* mask = (const float*)d_in[1];
  const float* qkvw = (const float*)d_in[2];
  const float* qb   = (const float*)d_in[3];
  const float* vb   = (const float*)d_in[4];
  const float* lsc  = (const float*)d_in[5];
  const float* w1   = (const float*)d_in[6];
  const float* b1   = (const float*)d_in[7];
  const float* w2   = (const float*)d_in[8];
  const float* pw   = (const float*)d_in[9];
  const float* pb   = (const float*)d_in[10];
  const float* ct   = (const float*)d_in[11];
  const int* rel    = (const int*)d_in[12];
  float* out = (float*)d_out;

  char* ws = (char*)d_ws;
  float* table  = (float*)(ws);
  float* bias16 = (float*)(ws + 16384);
  const size_t CHUNK_QKV = 8388608;  // bytes per Q/K/V chunk buffer
  u16* Qc = (u16*)(ws + (1 << 20));
  u16* Kc = (u16*)(ws + (1 << 20) + CHUNK_QKV);
  u16* Vc = (u16*)(ws + (1 << 20) + 2 * CHUNK_QKV);

  cpb_kernel<<<225, 256, 0, stream>>>(ct, w1, b1, w2, table);
  gather_kernel<<<128, 256, 0, stream>>>(table, rel, bias16);

  const int CHUNK_ROWS = 16384;  // 256 windows * 64 tokens
  for (int c = 0; c < 8; ++c) {
    float* outc = out + (size_t)c * CHUNK_ROWS * 256;
    gemm_qkv<<<dim3(128, 6), 256, 0, stream>>>(x, qkvw, qb, vb,
                                               c * CHUNK_ROWS, Qc, Kc, Vc);
    attn_proj<<<256, 256, 0, stream>>>(Qc, Kc, Vc, mask, bias16, lsc, pw, pb,
                                       outc);
  }
}

// Round 5
// 550.544 us; speedup vs baseline: 1.1469x; 1.1469x over previous
//
#include <hip/hip_runtime.h>
#include <hip/hip_bf16.h>

typedef unsigned short u16;
typedef unsigned int   u32;
typedef __attribute__((ext_vector_type(8))) short short8;   // 8 x bf16 bits (4 VGPR)
typedef __attribute__((ext_vector_type(4))) float f32x4;    // MFMA 16x16 accumulator

__device__ __forceinline__ float bf2f(u16 u) {
  union { u32 i; float f; } v; v.i = ((u32)u) << 16; return v.f;
}
// round-to-nearest-even f32 -> bf16 (finite inputs only)
__device__ __forceinline__ u16 f2bf(float f) {
  u32 u = __float_as_uint(f);
  u32 r = (u + 0x7fffu + ((u >> 16) & 1u)) >> 16;
  return (u16)r;
}
// load 8 consecutive fp32, convert to bf16 bits (two float4 vector loads)
__device__ __forceinline__ short8 loadcvt8(const float* __restrict__ p) {
  const float4 a = *(const float4*)(p);
  const float4 b = *(const float4*)(p + 4);
  short8 r;
  r[0] = (short)f2bf(a.x); r[1] = (short)f2bf(a.y);
  r[2] = (short)f2bf(a.z); r[3] = (short)f2bf(a.w);
  r[4] = (short)f2bf(b.x); r[5] = (short)f2bf(b.y);
  r[6] = (short)f2bf(b.z); r[7] = (short)f2bf(b.w);
  return r;
}

// ---------------------------------------------------------------------------
// CPB MLP: table[225][8] = relu(coords @ w1^T + b1) @ w2^T   (fp32 math)
// ---------------------------------------------------------------------------
__global__ __launch_bounds__(256) void cpb_kernel(
    const float* __restrict__ ct, const float* __restrict__ w1,
    const float* __restrict__ b1, const float* __restrict__ w2,
    float* __restrict__ table) {
  const int r = blockIdx.x;            // 0..224
  const int t = threadIdx.x;           // 0..255
  const int lane = t & 63, wave = t >> 6;
  const float c0 = ct[r * 2 + 0];
  const float c1 = ct[r * 2 + 1];
  float acc[8] = {0.f, 0.f, 0.f, 0.f, 0.f, 0.f, 0.f, 0.f};
  for (int j = t; j < 512; j += 256) {
    float hid = fmaxf(c0 * w1[j * 2] + c1 * w1[j * 2 + 1] + b1[j], 0.f);
#pragma unroll
    for (int hh = 0; hh < 8; ++hh) acc[hh] += hid * w2[hh * 512 + j];
  }
#pragma unroll
  for (int hh = 0; hh < 8; ++hh)
#pragma unroll
    for (int off = 1; off < 64; off <<= 1) acc[hh] += __shfl_xor(acc[hh], off);
  __shared__ float red[4][8];
  if (lane == 0)
#pragma unroll
    for (int hh = 0; hh < 8; ++hh) red[wave][hh] = acc[hh];
  __syncthreads();
  if (t < 8) table[r * 8 + t] = red[0][t] + red[1][t] + red[2][t] + red[3][t];
}

// bias16[h][i*64+j] = 16*sigmoid(table[rel_idx[i*64+j]][h])
__global__ __launch_bounds__(256) void gather_kernel(
    const float* __restrict__ table, const int* __restrict__ rel,
    float* __restrict__ bias16) {
  const int e = blockIdx.x * 256 + threadIdx.x;  // 8*4096 = 32768
  const int hh = e >> 12, ij = e & 4095;
  const float v = table[rel[ij] * 8 + hh];
  bias16[e] = 16.f * (1.f / (1.f + __expf(-v)));
}

// ---------------------------------------------------------------------------
// QKV GEMM: C[m][n] = sum_k x[row0+m][k]*w[n][k] + bias, scattered to
// Q/K/V [nw][H][64][32] bf16.  fp32 inputs -> bf16 LDS tiles.
// ---------------------------------------------------------------------------
#define BK 32
__global__ __launch_bounds__(256) void gemm_qkv(
    const float* __restrict__ X,   // full [131072][256] fp32
    const float* __restrict__ Wq,  // [768][256] fp32
    const float* __restrict__ qb, const float* __restrict__ vb,
    int row0,
    u16* __restrict__ Q, u16* __restrict__ K, u16* __restrict__ V) {
  __shared__ __attribute__((aligned(16))) u16 lA[128 * BK];
  __shared__ __attribute__((aligned(16))) u16 lB[128 * BK];
  const int tid = threadIdx.x;
  const int wave = tid >> 6, lane = tid & 63;
  const int l15 = lane & 15, l4 = lane >> 4;
  const int m0 = blockIdx.x * 128;
  const int n0 = blockIdx.y * 128;
  const int wm = (wave & 1) * 64;
  const int wn = (wave >> 1) * 64;
  const int sr = tid >> 1;          // staging row 0..127
  const int sc = (tid & 1) * 16;    // staging col 0 or 16

  f32x4 acc[4][4];
#pragma unroll
  for (int i = 0; i < 4; ++i)
#pragma unroll
    for (int j = 0; j < 4; ++j) acc[i][j] = (f32x4){0.f, 0.f, 0.f, 0.f};

  for (int k0 = 0; k0 < 256; k0 += BK) {
    __syncthreads();  // previous iter done reading LDS
    short8 a0 = loadcvt8(X  + (size_t)(row0 + m0 + sr) * 256 + k0 + sc);
    short8 a1 = loadcvt8(X  + (size_t)(row0 + m0 + sr) * 256 + k0 + sc + 8);
    short8 b0 = loadcvt8(Wq + (size_t)(n0 + sr) * 256 + k0 + sc);
    short8 b1 = loadcvt8(Wq + (size_t)(n0 + sr) * 256 + k0 + sc + 8);
    *(short8*)&lA[sr * BK + sc]     = a0;
    *(short8*)&lA[sr * BK + sc + 8] = a1;
    *(short8*)&lB[sr * BK + sc]     = b0;
    *(short8*)&lB[sr * BK + sc + 8] = b1;
    __syncthreads();

    short8 af[4], bf[4];
#pragma unroll
    for (int i = 0; i < 4; ++i)
      af[i] = *(const short8*)&lA[(wm + i * 16 + l15) * BK + l4 * 8];
#pragma unroll
    for (int j = 0; j < 4; ++j)
      bf[j] = *(const short8*)&lB[(wn + j * 16 + l15) * BK + l4 * 8];
#pragma unroll
    for (int i = 0; i < 4; ++i)
#pragma unroll
      for (int j = 0; j < 4; ++j)
        acc[i][j] = __builtin_amdgcn_mfma_f32_16x16x32_bf16(af[i], bf[j], acc[i][j], 0, 0, 0);
  }

  // epilogue: n -> (which, head, d); m -> (window b, token t)
#pragma unroll
  for (int i = 0; i < 4; ++i) {
    const int mrow = m0 + wm + i * 16 + l4 * 4;
#pragma unroll
    for (int j = 0; j < 4; ++j) {
      const int n = n0 + wn + j * 16 + l15;
      const int which = n >> 8;
      const int c = n & 255;
      const float bias = (which == 0) ? qb[c] : (which == 2) ? vb[c] : 0.f;
      u16* dst = (which == 0) ? Q : (which == 1) ? K : V;
      const int h = c >> 5, d = c & 31;
#pragma unroll
      for (int r = 0; r < 4; ++r) {
        const int m = mrow + r;
        const int b = m >> 6, t = m & 63;
        dst[(((size_t)b * 8 + h) * 64 + t) * 32 + d] = f2bf(acc[i][j][r] + bias);
      }
    }
  }
}

// ---------------------------------------------------------------------------
// Fused attention + proj: one block per window.  Per head: normalize q,k ->
// S=Qn.Kn^T (MFMA) -> *scale +bias +mask -> softmax -> P.V (MFMA) -> o_lds;
// then proj GEMM from o_lds, fp32 output.
// ---------------------------------------------------------------------------
__global__ __launch_bounds__(256) void attn_proj(
    const u16* __restrict__ Q, const u16* __restrict__ K, const u16* __restrict__ V,
    const float* __restrict__ mask,  // [64][64][64] fp32
    const float* __restrict__ bias16,// [8][4096] fp32
    const float* __restrict__ lsc,   // [8] fp32
    const float* __restrict__ Wp,    // [256][256] fp32
    const float* __restrict__ pb,    // [256] fp32
    float* __restrict__ out) {       // [nw*64][256] fp32 (chunk base)
  constexpr int OS = 264;  // o_lds row stride
  __shared__ __attribute__((aligned(16))) u16 q_lds[64 * 32];
  __shared__ __attribute__((aligned(16))) u16 k_lds[64 * 32];
  __shared__ __attribute__((aligned(16))) u16 vt_lds[32 * 72];
  __shared__ __attribute__((aligned(16))) u16 p_lds[64 * 72];
  __shared__ __attribute__((aligned(16))) u16 o_lds[64 * OS];

  const int b = blockIdx.x;        // chunk-local window id (chunk ≡ 0 mod 64)
  const int w = b & 63;            // mask window index
  const int tid = threadIdx.x;
  const int wave = tid >> 6, lane = tid & 63;
  const int l15 = lane & 15, l4 = lane >> 4;
  const int lrow = tid >> 2;        // 0..63
  const int lcol = (tid & 3) * 8;   // 0,8,16,24

  for (int h = 0; h < 8; ++h) {
    const size_t base = ((size_t)b * 8 + h) * 2048;
    __syncthreads();  // prev head done reading q/k/vt/p (cross-wave)

    {  // stage q (normalized), k (normalized), v^T
      short8 qv = *(const short8*)(Q + base + lrow * 32 + lcol);
      float f[8]; float ss = 0.f;
#pragma unroll
      for (int j = 0; j < 8; ++j) { f[j] = bf2f((u16)qv[j]); ss += f[j] * f[j]; }
      ss += __shfl_xor(ss, 1); ss += __shfl_xor(ss, 2);
      float inv = 1.f / fmaxf(sqrtf(ss), 1e-12f);
      short8 st;
#pragma unroll
      for (int j = 0; j < 8; ++j) st[j] = (short)f2bf(f[j] * inv);
      *(short8*)&q_lds[lrow * 32 + lcol] = st;

      short8 kv = *(const short8*)(K + base + lrow * 32 + lcol);
      ss = 0.f;
#pragma unroll
      for (int j = 0; j < 8; ++j) { f[j] = bf2f((u16)kv[j]); ss += f[j] * f[j]; }
      ss += __shfl_xor(ss, 1); ss += __shfl_xor(ss, 2);
      inv = 1.f / fmaxf(sqrtf(ss), 1e-12f);
#pragma unroll
      for (int j = 0; j < 8; ++j) st[j] = (short)f2bf(f[j] * inv);
      *(short8*)&k_lds[lrow * 32 + lcol] = st;

      short8 vv = *(const short8*)(V + base + lrow * 32 + lcol);
#pragma unroll
      for (int j = 0; j < 8; ++j) vt_lds[(lcol + j) * 72 + lrow] = (u16)vv[j];
    }
    __syncthreads();

    // S tiles: wave owns rows [wave*16, wave*16+16) x all 64 cols
    const float scale = expf(fminf(lsc[h], 4.60517018598809136804f));
    short8 aq = *(const short8*)&q_lds[(wave * 16 + l15) * 32 + l4 * 8];
    f32x4 s[4];
#pragma unroll
    for (int nb = 0; nb < 4; ++nb) {
      short8 bk = *(const short8*)&k_lds[(nb * 16 + l15) * 32 + l4 * 8];
      f32x4 z = {0.f, 0.f, 0.f, 0.f};
      s[nb] = __builtin_amdgcn_mfma_f32_16x16x32_bf16(aq, bk, z, 0, 0, 0);
    }

    const float* brow = bias16 + h * 4096;
    const float* mrow = mask + (size_t)w * 4096;
    float pm[4][4];  // [nb][r]
#pragma unroll
    for (int r = 0; r < 4; ++r) {
      const int i = wave * 16 + l4 * 4 + r;
      float v0[4]; float mx = -3.0e38f;
#pragma unroll
      for (int nb = 0; nb < 4; ++nb) {
        const int j = nb * 16 + l15;
        float sv = s[nb][r] * scale + brow[i * 64 + j] + mrow[i * 64 + j];
        v0[nb] = sv; mx = fmaxf(mx, sv);
      }
      mx = fmaxf(mx, __shfl_xor(mx, 1)); mx = fmaxf(mx, __shfl_xor(mx, 2));
      mx = fmaxf(mx, __shfl_xor(mx, 4)); mx = fmaxf(mx, __shfl_xor(mx, 8));
      float sum = 0.f;
#pragma unroll
      for (int nb = 0; nb < 4; ++nb) { v0[nb] = __expf(v0[nb] - mx); sum += v0[nb]; }
      sum += __shfl_xor(sum, 1); sum += __shfl_xor(sum, 2);
      sum += __shfl_xor(sum, 4); sum += __shfl_xor(sum, 8);
      const float isum = 1.f / sum;
#pragma unroll
      for (int nb = 0; nb < 4; ++nb) pm[nb][r] = v0[nb] * isum;
    }
#pragma unroll
    for (int nb = 0; nb < 4; ++nb)
#pragma unroll
      for (int r = 0; r < 4; ++r)
        p_lds[(wave * 16 + l4 * 4 + r) * 72 + nb * 16 + l15] = f2bf(pm[nb][r]);
    // NO barrier here: P rows read below (wave*16+l15) are written only by
    // this wave (wave*16 + l4*4+r); vt_lds was synced after staging.
    // Wave-internal LDS RAW is ordered by lgkmcnt.

    // O = P @ V : rows wave*16.., cols d 0..31 (2 n-tiles), K=64 (2 k-steps)
    f32x4 oa[2] = {{0.f, 0.f, 0.f, 0.f}, {0.f, 0.f, 0.f, 0.f}};
#pragma unroll
    for (int kb = 0; kb < 2; ++kb) {
      short8 pa = *(const short8*)&p_lds[(wave * 16 + l15) * 72 + kb * 32 + l4 * 8];
#pragma unroll
      for (int nb = 0; nb < 2; ++nb) {
        short8 vb8 = *(const short8*)&vt_lds[(nb * 16 + l15) * 72 + kb * 32 + l4 * 8];
        oa[nb] = __builtin_amdgcn_mfma_f32_16x16x32_bf16(pa, vb8, oa[nb], 0, 0, 0);
      }
    }
#pragma unroll
    for (int nb = 0; nb < 2; ++nb)
#pragma unroll
      for (int r = 0; r < 4; ++r) {
        const int m = wave * 16 + l4 * 4 + r;
        const int d = nb * 16 + l15;
        o_lds[m * OS + h * 32 + d] = f2bf(oa[nb][r]);
      }
  }
  __syncthreads();  // o_lds complete across all waves

  // proj: wave owns n-range [wave*64, wave*64+64), all 64 rows; K=256
  const int n0 = wave * 64;
  f32x4 pacc[4][4];
#pragma unroll
  for (int i = 0; i < 4; ++i)
#pragma unroll
    for (int j = 0; j < 4; ++j) pacc[i][j] = (f32x4){0.f, 0.f, 0.f, 0.f};
  for (int k0 = 0; k0 < 256; k0 += 32) {
    short8 afr[4];
#pragma unroll
    for (int mi = 0; mi < 4; ++mi)
      afr[mi] = *(const short8*)&o_lds[(mi * 16 + l15) * OS + k0 + l4 * 8];
#pragma unroll
    for (int nj = 0; nj < 4; ++nj) {
      short8 bfr = loadcvt8(Wp + (size_t)(n0 + nj * 16 + l15) * 256 + k0 + l4 * 8);
#pragma unroll
      for (int mi = 0; mi < 4; ++mi)
        pacc[mi][nj] = __builtin_amdgcn_mfma_f32_16x16x32_bf16(afr[mi], bfr, pacc[mi][nj], 0, 0, 0);
    }
  }
#pragma unroll
  for (int mi = 0; mi < 4; ++mi)
#pragma unroll
    for (int nj = 0; nj < 4; ++nj) {
      const int n = n0 + nj * 16 + l15;
      const float bias = pb[n];
#pragma unroll
      for (int r = 0; r < 4; ++r) {
        const int m = mi * 16 + l4 * 4 + r;
        out[((size_t)b * 64 + m) * 256 + n] = pacc[mi][nj][r] + bias;
      }
    }
}

// ---------------------------------------------------------------------------
// ws layout: [0,7.2K) table | [16K,147K) bias16 | [1M..] Qc/Kc/Vc.
// Chunk count chosen from ws_size: 1 chunk needs 1MB + 3*64MB = 202.4MB.
// ---------------------------------------------------------------------------
extern "C" void kernel_launch(void* const* d_in, const int* in_sizes, int n_in,
                              void* d_out, int out_size, void* d_ws, size_t ws_size,
                              hipStream_t stream) {
  (void)in_sizes; (void)n_in; (void)out_size;
  const float* x    = (const float*)d_in[0];
  const float* mask = (const float*)d_in[1];
  const float* qkvw = (const float*)d_in[2];
  const float* qb   = (const float*)d_in[3];
  const float* vb   = (const float*)d_in[4];
  const float* lsc  = (const float*)d_in[5];
  const float* w1   = (const float*)d_in[6];
  const float* b1   = (const float*)d_in[7];
  const float* w2   = (const float*)d_in[8];
  const float* pw   = (const float*)d_in[9];
  const float* pb   = (const float*)d_in[10];
  const float* ct   = (const float*)d_in[11];
  const int* rel    = (const int*)d_in[12];
  float* out = (float*)d_out;

  char* ws = (char*)d_ws;
  float* table  = (float*)(ws);
  float* bias16 = (float*)(ws + 16384);

  // pick chunking: smallest nch in {1,2,4,8} fitting ws_size
  const size_t FULL_QKV = 67108864ull;  // one full Q (or K or V) in bytes
  int nch = 8;
  for (int c = 1; c <= 8; c <<= 1) {
    if (ws_size >= (1ull << 20) + 3ull * (FULL_QKV / c)) { nch = c; break; }
  }
  const size_t CHUNK_QKV = FULL_QKV / nch;
  u16* Qc = (u16*)(ws + (1 << 20));
  u16* Kc = (u16*)(ws + (1 << 20) + CHUNK_QKV);
  u16* Vc = (u16*)(ws + (1 << 20) + 2 * CHUNK_QKV);

  cpb_kernel<<<225, 256, 0, stream>>>(ct, w1, b1, w2, table);
  gather_kernel<<<128, 256, 0, stream>>>(table, rel, bias16);

  const int CHUNK_WIN  = 2048 / nch;        // windows per chunk (mult of 64)
  const int CHUNK_ROWS = CHUNK_WIN * 64;    // token rows per chunk
  for (int c = 0; c < nch; ++c) {
    float* outc = out + (size_t)c * CHUNK_ROWS * 256;
    gemm_qkv<<<dim3(CHUNK_ROWS / 128, 6), 256, 0, stream>>>(
        x, qkvw, qb, vb, c * CHUNK_ROWS, Qc, Kc, Vc);
    attn_proj<<<CHUNK_WIN, 256, 0, stream>>>(Qc, Kc, Vc, mask, bias16, lsc,
                                             pw, pb, outc);
  }
}

// Round 6
// 545.309 us; speedup vs baseline: 1.1579x; 1.0096x over previous
//
#include <hip/hip_runtime.h>
#include <hip/hip_bf16.h>

typedef unsigned short u16;
typedef unsigned int   u32;
typedef __attribute__((ext_vector_type(8))) short short8;   // 8 x bf16 bits (4 VGPR)
typedef __attribute__((ext_vector_type(4))) short short4v;  // 4 x bf16 bits (8 B)
typedef __attribute__((ext_vector_type(4))) float f32x4;    // MFMA 16x16 accumulator

__device__ __forceinline__ float bf2f(u16 u) {
  union { u32 i; float f; } v; v.i = ((u32)u) << 16; return v.f;
}
// round-to-nearest-even f32 -> bf16 (finite inputs only)
__device__ __forceinline__ u16 f2bf(float f) {
  u32 u = __float_as_uint(f);
  u32 r = (u + 0x7fffu + ((u >> 16) & 1u)) >> 16;
  return (u16)r;
}

// ---------------------------------------------------------------------------
// Weight pre-convert: qkv_w [768][256] fp32 -> bf16, proj_w [256][256] -> bf16
// ---------------------------------------------------------------------------
__global__ __launch_bounds__(256) void wcvt_kernel(
    const float* __restrict__ qkvw, const float* __restrict__ pw,
    u16* __restrict__ wq, u16* __restrict__ wp) {
  const int e = (blockIdx.x * 256 + threadIdx.x) * 4;  // 256 blocks -> 262144
  if (e < 196608) {
    const float4 v = *(const float4*)(qkvw + e);
    short4v o; o[0]=(short)f2bf(v.x); o[1]=(short)f2bf(v.y);
    o[2]=(short)f2bf(v.z); o[3]=(short)f2bf(v.w);
    *(short4v*)(wq + e) = o;
  } else {
    const int e2 = e - 196608;
    const float4 v = *(const float4*)(pw + e2);
    short4v o; o[0]=(short)f2bf(v.x); o[1]=(short)f2bf(v.y);
    o[2]=(short)f2bf(v.z); o[3]=(short)f2bf(v.w);
    *(short4v*)(wp + e2) = o;
  }
}

// ---------------------------------------------------------------------------
// CPB MLP: table[225][8] = relu(coords @ w1^T + b1) @ w2^T   (fp32 math)
// ---------------------------------------------------------------------------
__global__ __launch_bounds__(256) void cpb_kernel(
    const float* __restrict__ ct, const float* __restrict__ w1,
    const float* __restrict__ b1, const float* __restrict__ w2,
    float* __restrict__ table) {
  const int r = blockIdx.x;            // 0..224
  const int t = threadIdx.x;           // 0..255
  const int lane = t & 63, wave = t >> 6;
  const float c0 = ct[r * 2 + 0];
  const float c1 = ct[r * 2 + 1];
  float acc[8] = {0.f, 0.f, 0.f, 0.f, 0.f, 0.f, 0.f, 0.f};
  for (int j = t; j < 512; j += 256) {
    float hid = fmaxf(c0 * w1[j * 2] + c1 * w1[j * 2 + 1] + b1[j], 0.f);
#pragma unroll
    for (int hh = 0; hh < 8; ++hh) acc[hh] += hid * w2[hh * 512 + j];
  }
#pragma unroll
  for (int hh = 0; hh < 8; ++hh)
#pragma unroll
    for (int off = 1; off < 64; off <<= 1) acc[hh] += __shfl_xor(acc[hh], off);
  __shared__ float red[4][8];
  if (lane == 0)
#pragma unroll
    for (int hh = 0; hh < 8; ++hh) red[wave][hh] = acc[hh];
  __syncthreads();
  if (t < 8) table[r * 8 + t] = red[0][t] + red[1][t] + red[2][t] + red[3][t];
}

// bias16[h][i*64+j] = 16*sigmoid(table[rel_idx[i*64+j]][h])
__global__ __launch_bounds__(256) void gather_kernel(
    const float* __restrict__ table, const int* __restrict__ rel,
    float* __restrict__ bias16) {
  const int e = blockIdx.x * 256 + threadIdx.x;  // 8*4096 = 32768
  const int hh = e >> 12, ij = e & 4095;
  const float v = table[rel[ij] * 8 + hh];
  bias16[e] = 16.f * (1.f / (1.f + __expf(-v)));
}

// ---------------------------------------------------------------------------
// QKV GEMM, restructured: grid = m-tiles only.  A (x) staged ONCE for all
// K=256 (64 KB LDS, x fetched exactly once, converted once); 6 n-tiles
// looped internally with B-frags read directly from L2-resident bf16 W.
// One __syncthreads per block.
// ---------------------------------------------------------------------------
__global__ __launch_bounds__(256) void gemm_qkv(
    const float* __restrict__ X,   // [131072][256] fp32
    const u16* __restrict__ Wb,    // [768][256] bf16 (pre-converted)
    const float* __restrict__ qb, const float* __restrict__ vb,
    int row0,
    u16* __restrict__ Q, u16* __restrict__ K, u16* __restrict__ V) {
  __shared__ __attribute__((aligned(16))) u16 lA[8][128][32];  // 64 KB
  const int tid = threadIdx.x;
  const int wave = tid >> 6, lane = tid & 63;
  const int l15 = lane & 15, l4 = lane >> 4;
  const int m0 = blockIdx.x * 128;
  const int wm  = (wave & 1) * 64;   // wave m-offset within tile
  const int wn64 = (wave >> 1) * 64; // wave n-offset within n-tile

  // ---- stage A once: thread t covers 8B col-chunk cq, rows rlo + s*32 ----
  // LDS write banks: 16*(row&1) + 2*cq + j -> all 32 banks uniform (no conflict)
  const int cq  = tid & 7;          // 8 chunks of 4 fp32 = 32 cols
  const int rlo = tid >> 3;         // 0..31
#pragma unroll
  for (int kf = 0; kf < 8; ++kf) {
#pragma unroll
    for (int s = 0; s < 4; ++s) {
      const int row = rlo + s * 32;
      const float4 xv = *(const float4*)(X + (size_t)(row0 + m0 + row) * 256 + kf * 32 + cq * 4);
      short4v t4;
      t4[0] = (short)f2bf(xv.x); t4[1] = (short)f2bf(xv.y);
      t4[2] = (short)f2bf(xv.z); t4[3] = (short)f2bf(xv.w);
      *(short4v*)&lA[kf][row][cq * 4] = t4;
    }
  }
  __syncthreads();

  // ---- n-loop over 6 tiles of 128 cols of QKV ----
  for (int nt = 0; nt < 6; ++nt) {
    const int n0 = nt * 128;
    f32x4 acc[4][4];
#pragma unroll
    for (int i = 0; i < 4; ++i)
#pragma unroll
      for (int j = 0; j < 4; ++j) acc[i][j] = (f32x4){0.f, 0.f, 0.f, 0.f};

#pragma unroll
    for (int kf = 0; kf < 8; ++kf) {
      short8 af[4], bf[4];
#pragma unroll
      for (int i = 0; i < 4; ++i)
        af[i] = *(const short8*)&lA[kf][wm + i * 16 + l15][l4 * 8];
#pragma unroll
      for (int j = 0; j < 4; ++j)
        bf[j] = *(const short8*)(Wb + (size_t)(n0 + wn64 + j * 16 + l15) * 256 + kf * 32 + l4 * 8);
#pragma unroll
      for (int i = 0; i < 4; ++i)
#pragma unroll
        for (int j = 0; j < 4; ++j)
          acc[i][j] = __builtin_amdgcn_mfma_f32_16x16x32_bf16(af[i], bf[j], acc[i][j], 0, 0, 0);
    }

    // epilogue: n -> (which, head, d); m -> (window b, token t)
#pragma unroll
    for (int i = 0; i < 4; ++i) {
      const int mrow = m0 + wm + i * 16 + l4 * 4;
#pragma unroll
      for (int j = 0; j < 4; ++j) {
        const int n = n0 + wn64 + j * 16 + l15;
        const int which = n >> 8;
        const int c = n & 255;
        const float bias = (which == 0) ? qb[c] : (which == 2) ? vb[c] : 0.f;
        u16* dst = (which == 0) ? Q : (which == 1) ? K : V;
        const int h = c >> 5, d = c & 31;
#pragma unroll
        for (int r = 0; r < 4; ++r) {
          const int m = mrow + r;
          const int b = m >> 6, t = m & 63;
          dst[(((size_t)b * 8 + h) * 64 + t) * 32 + d] = f2bf(acc[i][j][r] + bias);
        }
      }
    }
  }
}

// ---------------------------------------------------------------------------
// Fused attention + proj: one block per window.  Per head: normalize q,k ->
// S=Qn.Kn^T (MFMA) -> *scale +bias +mask -> softmax -> P.V (MFMA) -> o_lds;
// then proj GEMM from o_lds (bf16 weights), fp32 output.
// ---------------------------------------------------------------------------
__global__ __launch_bounds__(256) void attn_proj(
    const u16* __restrict__ Q, const u16* __restrict__ K, const u16* __restrict__ V,
    const float* __restrict__ mask,  // [64][64][64] fp32
    const float* __restrict__ bias16,// [8][4096] fp32
    const float* __restrict__ lsc,   // [8] fp32
    const u16* __restrict__ Wpb,     // [256][256] bf16 (pre-converted)
    const float* __restrict__ pb,    // [256] fp32
    float* __restrict__ out) {       // [nw*64][256] fp32 (chunk base)
  constexpr int OS = 264;  // o_lds row stride
  __shared__ __attribute__((aligned(16))) u16 q_lds[64 * 32];
  __shared__ __attribute__((aligned(16))) u16 k_lds[64 * 32];
  __shared__ __attribute__((aligned(16))) u16 vt_lds[32 * 72];
  __shared__ __attribute__((aligned(16))) u16 p_lds[64 * 72];
  __shared__ __attribute__((aligned(16))) u16 o_lds[64 * OS];

  const int b = blockIdx.x;        // chunk-local window id (chunk ≡ 0 mod 64)
  const int w = b & 63;            // mask window index
  const int tid = threadIdx.x;
  const int wave = tid >> 6, lane = tid & 63;
  const int l15 = lane & 15, l4 = lane >> 4;
  const int lrow = tid >> 2;        // 0..63
  const int lcol = (tid & 3) * 8;   // 0,8,16,24

  for (int h = 0; h < 8; ++h) {
    const size_t base = ((size_t)b * 8 + h) * 2048;
    __syncthreads();  // prev head done reading q/k/vt/p (cross-wave)

    {  // stage q (normalized), k (normalized), v^T
      short8 qv = *(const short8*)(Q + base + lrow * 32 + lcol);
      float f[8]; float ss = 0.f;
#pragma unroll
      for (int j = 0; j < 8; ++j) { f[j] = bf2f((u16)qv[j]); ss += f[j] * f[j]; }
      ss += __shfl_xor(ss, 1); ss += __shfl_xor(ss, 2);
      float inv = 1.f / fmaxf(sqrtf(ss), 1e-12f);
      short8 st;
#pragma unroll
      for (int j = 0; j < 8; ++j) st[j] = (short)f2bf(f[j] * inv);
      *(short8*)&q_lds[lrow * 32 + lcol] = st;

      short8 kv = *(const short8*)(K + base + lrow * 32 + lcol);
      ss = 0.f;
#pragma unroll
      for (int j = 0; j < 8; ++j) { f[j] = bf2f((u16)kv[j]); ss += f[j] * f[j]; }
      ss += __shfl_xor(ss, 1); ss += __shfl_xor(ss, 2);
      inv = 1.f / fmaxf(sqrtf(ss), 1e-12f);
#pragma unroll
      for (int j = 0; j < 8; ++j) st[j] = (short)f2bf(f[j] * inv);
      *(short8*)&k_lds[lrow * 32 + lcol] = st;

      short8 vv = *(const short8*)(V + base + lrow * 32 + lcol);
#pragma unroll
      for (int j = 0; j < 8; ++j) vt_lds[(lcol + j) * 72 + lrow] = (u16)vv[j];
    }
    __syncthreads();

    // S tiles: wave owns rows [wave*16, wave*16+16) x all 64 cols
    const float scale = expf(fminf(lsc[h], 4.60517018598809136804f));
    short8 aq = *(const short8*)&q_lds[(wave * 16 + l15) * 32 + l4 * 8];
    f32x4 s[4];
#pragma unroll
    for (int nb = 0; nb < 4; ++nb) {
      short8 bk = *(const short8*)&k_lds[(nb * 16 + l15) * 32 + l4 * 8];
      f32x4 z = {0.f, 0.f, 0.f, 0.f};
      s[nb] = __builtin_amdgcn_mfma_f32_16x16x32_bf16(aq, bk, z, 0, 0, 0);
    }

    const float* brow = bias16 + h * 4096;
    const float* mrow = mask + (size_t)w * 4096;
    float pm[4][4];  // [nb][r]
#pragma unroll
    for (int r = 0; r < 4; ++r) {
      const int i = wave * 16 + l4 * 4 + r;
      float v0[4]; float mx = -3.0e38f;
#pragma unroll
      for (int nb = 0; nb < 4; ++nb) {
        const int j = nb * 16 + l15;
        float sv = s[nb][r] * scale + brow[i * 64 + j] + mrow[i * 64 + j];
        v0[nb] = sv; mx = fmaxf(mx, sv);
      }
      mx = fmaxf(mx, __shfl_xor(mx, 1)); mx = fmaxf(mx, __shfl_xor(mx, 2));
      mx = fmaxf(mx, __shfl_xor(mx, 4)); mx = fmaxf(mx, __shfl_xor(mx, 8));
      float sum = 0.f;
#pragma unroll
      for (int nb = 0; nb < 4; ++nb) { v0[nb] = __expf(v0[nb] - mx); sum += v0[nb]; }
      sum += __shfl_xor(sum, 1); sum += __shfl_xor(sum, 2);
      sum += __shfl_xor(sum, 4); sum += __shfl_xor(sum, 8);
      const float isum = 1.f / sum;
#pragma unroll
      for (int nb = 0; nb < 4; ++nb) pm[nb][r] = v0[nb] * isum;
    }
#pragma unroll
    for (int nb = 0; nb < 4; ++nb)
#pragma unroll
      for (int r = 0; r < 4; ++r)
        p_lds[(wave * 16 + l4 * 4 + r) * 72 + nb * 16 + l15] = f2bf(pm[nb][r]);
    // no barrier: P rows read below are the rows this wave wrote (lgkmcnt
    // orders wave-internal LDS RAW); vt_lds was synced after staging.

    // O = P @ V : rows wave*16.., cols d 0..31 (2 n-tiles), K=64 (2 k-steps)
    f32x4 oa[2] = {{0.f, 0.f, 0.f, 0.f}, {0.f, 0.f, 0.f, 0.f}};
#pragma unroll
    for (int kb = 0; kb < 2; ++kb) {
      short8 pa = *(const short8*)&p_lds[(wave * 16 + l15) * 72 + kb * 32 + l4 * 8];
#pragma unroll
      for (int nb = 0; nb < 2; ++nb) {
        short8 vb8 = *(const short8*)&vt_lds[(nb * 16 + l15) * 72 + kb * 32 + l4 * 8];
        oa[nb] = __builtin_amdgcn_mfma_f32_16x16x32_bf16(pa, vb8, oa[nb], 0, 0, 0);
      }
    }
#pragma unroll
    for (int nb = 0; nb < 2; ++nb)
#pragma unroll
      for (int r = 0; r < 4; ++r) {
        const int m = wave * 16 + l4 * 4 + r;
        const int d = nb * 16 + l15;
        o_lds[m * OS + h * 32 + d] = f2bf(oa[nb][r]);
      }
  }
  __syncthreads();  // o_lds complete across all waves

  // proj: wave owns n-range [wave*64, wave*64+64), all 64 rows; K=256
  const int n0 = wave * 64;
  f32x4 pacc[4][4];
#pragma unroll
  for (int i = 0; i < 4; ++i)
#pragma unroll
    for (int j = 0; j < 4; ++j) pacc[i][j] = (f32x4){0.f, 0.f, 0.f, 0.f};
  for (int k0 = 0; k0 < 256; k0 += 32) {
    short8 afr[4];
#pragma unroll
    for (int mi = 0; mi < 4; ++mi)
      afr[mi] = *(const short8*)&o_lds[(mi * 16 + l15) * OS + k0 + l4 * 8];
#pragma unroll
    for (int nj = 0; nj < 4; ++nj) {
      short8 bfr = *(const short8*)(Wpb + (size_t)(n0 + nj * 16 + l15) * 256 + k0 + l4 * 8);
#pragma unroll
      for (int mi = 0; mi < 4; ++mi)
        pacc[mi][nj] = __builtin_amdgcn_mfma_f32_16x16x32_bf16(afr[mi], bfr, pacc[mi][nj], 0, 0, 0);
    }
  }
#pragma unroll
  for (int mi = 0; mi < 4; ++mi)
#pragma unroll
    for (int nj = 0; nj < 4; ++nj) {
      const int n = n0 + nj * 16 + l15;
      const float bias = pb[n];
#pragma unroll
      for (int r = 0; r < 4; ++r) {
        const int m = mi * 16 + l4 * 4 + r;
        out[((size_t)b * 64 + m) * 256 + n] = pacc[mi][nj][r] + bias;
      }
    }
}

// ---------------------------------------------------------------------------
// ws layout: [0,16K) table | [16K,147K) bias16 | [256K,649K) Wqkv bf16 |
// [704K,832K) Wproj bf16 | [1M..] Qc/Kc/Vc (full: 1M + 192M)
// ---------------------------------------------------------------------------
extern "C" void kernel_launch(void* const* d_in, const int* in_sizes, int n_in,
                              void* d_out, int out_size, void* d_ws, size_t ws_size,
                              hipStream_t stream) {
  (void)in_sizes; (void)n_in; (void)out_size;
  const float* x    = (const float*)d_in[0];
  const float* mask = (const float*)d_in[1];
  const float* qkvw = (const float*)d_in[2];
  const float* qb   = (const float*)d_in[3];
  const float* vb   = (const float*)d_in[4];
  const float* lsc  = (const float*)d_in[5];
  const float* w1   = (const float*)d_in[6];
  const float* b1   = (const float*)d_in[7];
  const float* w2   = (const float*)d_in[8];
  const float* pw   = (const float*)d_in[9];
  const float* pb   = (const float*)d_in[10];
  const float* ct   = (const float*)d_in[11];
  const int* rel    = (const int*)d_in[12];
  float* out = (float*)d_out;

  char* ws = (char*)d_ws;
  float* table  = (float*)(ws);
  float* bias16 = (float*)(ws + 16384);
  u16* Wqb = (u16*)(ws + 262144);   // 393,216 B
  u16* Wpb = (u16*)(ws + 720896);   // 131,072 B

  // pick chunking: smallest nch in {1,2,4,8} fitting ws_size
  const size_t FULL_QKV = 67108864ull;  // one full Q (or K or V) in bytes
  int nch = 8;
  for (int c = 1; c <= 8; c <<= 1) {
    if (ws_size >= (1ull << 20) + 3ull * (FULL_QKV / c)) { nch = c; break; }
  }
  const size_t CHUNK_QKV = FULL_QKV / nch;
  u16* Qc = (u16*)(ws + (1 << 20));
  u16* Kc = (u16*)(ws + (1 << 20) + CHUNK_QKV);
  u16* Vc = (u16*)(ws + (1 << 20) + 2 * CHUNK_QKV);

  wcvt_kernel<<<256, 256, 0, stream>>>(qkvw, pw, Wqb, Wpb);
  cpb_kernel<<<225, 256, 0, stream>>>(ct, w1, b1, w2, table);
  gather_kernel<<<128, 256, 0, stream>>>(table, rel, bias16);

  const int CHUNK_WIN  = 2048 / nch;        // windows per chunk (mult of 64)
  const int CHUNK_ROWS = CHUNK_WIN * 64;    // token rows per chunk
  for (int c = 0; c < nch; ++c) {
    float* outc = out + (size_t)c * CHUNK_ROWS * 256;
    gemm_qkv<<<CHUNK_ROWS / 128, 256, 0, stream>>>(
        x, Wqb, qb, vb, c * CHUNK_ROWS, Qc, Kc, Vc);
    attn_proj<<<CHUNK_WIN, 256, 0, stream>>>(Qc, Kc, Vc, mask, bias16, lsc,
                                             Wpb, pb, outc);
  }
}